// Round 8
// baseline (147.015 us; speedup 1.0000x reference)
//
#include <hip/hip_runtime.h>
#include <math.h>

// ChamferLikeDistanceLoss on MI355X (gfx950)
// B=4, 1x64x64 fp32. out = mean_i min_j |g_i - b_j| + mean_j min_i |g_i - b_j|
//
// R8: DECISIVE PROBE. R5/R6/R7 all ~73-75us; issue model says ring ~3us but
// bookkeeping says kernel ~20us. Theories: (A) ring has ~6x unmodeled cost,
// (B) 512-deep same-address atomic rendezvous tail, (C) harness floor.
// This round: repeat ONLY the ring rep=17 times (runtime arg -> no CSE; min
// is idempotent and each pass is a full 64-rotation cycle -> output is
// bit-identical). Slope (dur-74.3)/16 = true marginal ring cost; the kernel
// now also exceeds the 39.4us fills and becomes visible in rocprof top-5.
// Predict: issue-bound -> dur ~122-128 (kernel ~55); mystery-A -> dur 350+.

#define N_PIX 4096

__device__ __forceinline__ float wave_ror1(float x) {
    return __int_as_float(__builtin_amdgcn_mov_dpp(__float_as_int(x),
                                                   0x13C, 0xF, 0xF, true));
}

__device__ __forceinline__ float sobel3(float t, float c, float b, int lane) {
    const float tl = (lane > 0)  ? __shfl_up(t, 1)   : 0.f;
    const float cl = (lane > 0)  ? __shfl_up(c, 1)   : 0.f;
    const float bl = (lane > 0)  ? __shfl_up(b, 1)   : 0.f;
    const float tr = (lane < 63) ? __shfl_down(t, 1) : 0.f;
    const float cr = (lane < 63) ? __shfl_down(c, 1) : 0.f;
    const float br = (lane < 63) ? __shfl_down(b, 1) : 0.f;
    const float gx = (tl - tr) + 2.f * (cl - cr) + (bl - br);
    const float gy = (tl + 2.f * t + tr) - (bl + 2.f * b + br);
    return sqrtf(gx * gx + gy * gy + 1e-8f);
}

__global__ __launch_bounds__(256) void chamfer_fused_kernel(
    const float* __restrict__ depth, const float* __restrict__ bnd,
    float* __restrict__ out, int blocks_per_dir, float inv_count, int rep)
{
    __shared__ float qmin[4][64];

    const int tid  = threadIdx.x;
    const int lane = tid & 63;
    const int w    = tid >> 6;
    const int bx   = blockIdx.x;
    const int dir  = (bx >= blocks_per_dir) ? 1 : 0;
    const int rem  = dir ? (bx - blocks_per_dir) : bx;
    const int batch = rem >> 6;
    const int qblk  = rem & 63;

    const float* __restrict__ db = depth + batch * N_PIX;
    const float* __restrict__ bb = bnd   + batch * N_PIX;

    float q;
    float r[16];

    if (dir == 0) {
        const float c = db[qblk * 64 + lane];
        const float t = (qblk > 0)  ? db[(qblk - 1) * 64 + lane] : 0.f;
        const float b = (qblk < 63) ? db[(qblk + 1) * 64 + lane] : 0.f;
        q = sobel3(t, c, b, lane);
        const float4* __restrict__ r4 = (const float4*)bb;
        #pragma unroll
        for (int k = 0; k < 4; ++k) {
            const float4 v = r4[w * 256 + k * 64 + lane];
            r[4 * k + 0] = v.x; r[4 * k + 1] = v.y;
            r[4 * k + 2] = v.z; r[4 * k + 3] = v.w;
        }
    } else {
        q = bb[qblk * 64 + lane];
        const int y0 = w * 16;
        float c = db[y0 * 64 + lane];
        float t = (y0 > 0) ? db[(y0 - 1) * 64 + lane] : 0.f;
        #pragma unroll
        for (int k = 0; k < 16; ++k) {
            const int y = y0 + k;
            const float b = (y < 63) ? db[(y + 1) * 64 + lane] : 0.f;
            r[k] = sobel3(t, c, b, lane);
            t = c; c = b;
        }
    }

    // Ring, repeated rep times. Each pass = exactly 64 rotations so (q,m)
    // come home; min across passes is idempotent -> identical result.
    float m = 1e30f;
    for (int rr = 0; rr < rep; ++rr) {
        for (int step = 0; step < 64; ++step) {
            const float q_next = wave_ror1(q);
            float t0 = 1e30f, t1 = 1e30f;
            #pragma unroll
            for (int k = 0; k < 16; k += 4) {
                t0 = fminf(fminf(t0, fabsf(q - r[k + 0])), fabsf(q - r[k + 1]));
                t1 = fminf(fminf(t1, fabsf(q - r[k + 2])), fabsf(q - r[k + 3]));
            }
            m = fminf(m, fminf(t0, t1));
            m = wave_ror1(m);
            q = q_next;
        }
    }

    qmin[w][lane] = m;
    __syncthreads();

    if (w == 0) {
        float mq = fminf(fminf(qmin[0][lane], qmin[1][lane]),
                         fminf(qmin[2][lane], qmin[3][lane]));
        #pragma unroll
        for (int o = 32; o > 0; o >>= 1) mq += __shfl_down(mq, o);
        if (lane == 0) {
            const float val = mq * inv_count;
            const unsigned old = atomicCAS((unsigned*)out, 0xAAAAAAAAu,
                                           __float_as_uint(val));
            if (old != 0xAAAAAAAAu) atomicAdd(out, val);
        }
    }
}

extern "C" void kernel_launch(void* const* d_in, const int* in_sizes, int n_in,
                              void* d_out, int out_size, void* d_ws, size_t ws_size,
                              hipStream_t stream) {
    const float* depth = (const float*)d_in[0];
    const float* bnd   = (const float*)d_in[1];
    float* out = (float*)d_out;

    const int B = in_sizes[0] / N_PIX;          // 4
    const int blocks_per_dir = B * 64;          // 256
    const float inv_count = 1.0f / (float)(B * N_PIX);

    hipLaunchKernelGGL(chamfer_fused_kernel, dim3(2 * blocks_per_dir), dim3(256),
                       0, stream, depth, bnd, out, blocks_per_dir, inv_count,
                       /*rep=*/17);
}

// Round 9
// 76.435 us; speedup vs baseline: 1.9234x; 1.9234x over previous
//
#include <hip/hip_runtime.h>
#include <math.h>

// ChamferLikeDistanceLoss on MI355X (gfx950)
// B=4, 1x64x64 fp32. out = mean_i min_j |g_i - b_j| + mean_j min_i |g_i - b_j|
//
// R9: compute identical to R7 (ring via DPP wave_ror); epilogue = 3-level
// 8-ary atomic tree.
//  - R8 probe: ring = 4.54us/pass (near issue floor); kernel(rep=1) ~ 30us
//    => K0 ~ 26us non-ring. Every variant R3-R7 ended in a ~512-deep
//    same-cacheline atomic RMW chain (adds/CAS/counter) ~ 100-130cy each
//    ~ 25us -- matches K0. R6 was neutral because its counter was still
//    512-deep. Fix: tree with depth<=16 RMWs per line, parallel across
//    64 distinct 128B-spaced lines: 512 -> 64 leaves -> 8 mids -> 1 final.
//  - CAS-or-add absorbs the 0xAA poison at every line (also correct if ws
//    is zeroed); ACQ_REL arrival counters give finalizers visibility of
//    children's adds. Last finalizer writes d_out once. No memsets.

#define N_PIX 4096
#define POISON_U 0xAAAAAAAAu

__device__ __forceinline__ float wave_ror1(float x) {
    return __int_as_float(__builtin_amdgcn_mov_dpp(__float_as_int(x),
                                                   0x13C, 0xF, 0xF, true));
}

__device__ __forceinline__ float sobel3(float t, float c, float b, int lane) {
    const float tl = (lane > 0)  ? __shfl_up(t, 1)   : 0.f;
    const float cl = (lane > 0)  ? __shfl_up(c, 1)   : 0.f;
    const float bl = (lane > 0)  ? __shfl_up(b, 1)   : 0.f;
    const float tr = (lane < 63) ? __shfl_down(t, 1) : 0.f;
    const float cr = (lane < 63) ? __shfl_down(c, 1) : 0.f;
    const float br = (lane < 63) ? __shfl_down(b, 1) : 0.f;
    const float gx = (tl - tr) + 2.f * (cl - cr) + (bl - br);
    const float gy = (tl + 2.f * t + tr) - (bl + 2.f * b + br);
    return sqrtf(gx * gx + gy * gy + 1e-8f);
}

__device__ __forceinline__ void cas_or_add(float* line, float val) {
    const unsigned old = atomicCAS((unsigned*)line, POISON_U,
                                   __float_as_uint(val));
    if (old != POISON_U) atomicAdd(line, val);
}

// Arrival counter: returns true for the k-th (last) arriver. Release orders
// the caller's prior line-RMW; acquire (on the winning read) makes children's
// RMWs visible to the finalizer's subsequent atomic read.
__device__ __forceinline__ bool arrive(unsigned* cnt, unsigned k) {
    const unsigned c = __hip_atomic_fetch_add(cnt, 1u, __ATOMIC_ACQ_REL,
                                              __HIP_MEMORY_SCOPE_AGENT);
    return (c == POISON_U + (k - 1)) || (c == (k - 1));
}

__device__ __forceinline__ float aread(float* line) {
    return __hip_atomic_fetch_add(line, 0.0f, __ATOMIC_ACQUIRE,
                                  __HIP_MEMORY_SCOPE_AGENT);
}

__global__ __launch_bounds__(256) void chamfer_fused_kernel(
    const float* __restrict__ depth, const float* __restrict__ bnd,
    float* __restrict__ out, float* __restrict__ ws,
    int blocks_per_dir, float inv_count)
{
    __shared__ float qmin[4][64];

    const int tid  = threadIdx.x;
    const int lane = tid & 63;
    const int w    = tid >> 6;
    const int bx   = blockIdx.x;
    const int dir  = (bx >= blocks_per_dir) ? 1 : 0;
    const int rem  = dir ? (bx - blocks_per_dir) : bx;
    const int batch = rem >> 6;
    const int qblk  = rem & 63;

    const float* __restrict__ db = depth + batch * N_PIX;
    const float* __restrict__ bb = bnd   + batch * N_PIX;

    float q;
    float r[16];

    if (dir == 0) {
        const float c = db[qblk * 64 + lane];
        const float t = (qblk > 0)  ? db[(qblk - 1) * 64 + lane] : 0.f;
        const float b = (qblk < 63) ? db[(qblk + 1) * 64 + lane] : 0.f;
        q = sobel3(t, c, b, lane);
        const float4* __restrict__ r4 = (const float4*)bb;
        #pragma unroll
        for (int k = 0; k < 4; ++k) {
            const float4 v = r4[w * 256 + k * 64 + lane];
            r[4 * k + 0] = v.x; r[4 * k + 1] = v.y;
            r[4 * k + 2] = v.z; r[4 * k + 3] = v.w;
        }
    } else {
        q = bb[qblk * 64 + lane];
        const int y0 = w * 16;
        float c = db[y0 * 64 + lane];
        float t = (y0 > 0) ? db[(y0 - 1) * 64 + lane] : 0.f;
        #pragma unroll
        for (int k = 0; k < 16; ++k) {
            const int y = y0 + k;
            const float b = (y < 63) ? db[(y + 1) * 64 + lane] : 0.f;
            r[k] = sobel3(t, c, b, lane);
            t = c; c = b;
        }
    }

    // Ring scan (proven, absmax <= 1 bf16 ulp): (q,m) rotate via DPP.
    float m = 1e30f;
    for (int step = 0; step < 64; ++step) {
        const float q_next = wave_ror1(q);
        float t0 = 1e30f, t1 = 1e30f;
        #pragma unroll
        for (int k = 0; k < 16; k += 4) {
            t0 = fminf(fminf(t0, fabsf(q - r[k + 0])), fabsf(q - r[k + 1]));
            t1 = fminf(fminf(t1, fabsf(q - r[k + 2])), fabsf(q - r[k + 3]));
        }
        m = fminf(m, fminf(t0, t1));
        m = wave_ror1(m);
        q = q_next;
    }

    qmin[w][lane] = m;
    __syncthreads();

    if (w == 0) {
        float mq = fminf(fminf(qmin[0][lane], qmin[1][lane]),
                         fminf(qmin[2][lane], qmin[3][lane]));
        #pragma unroll
        for (int o = 32; o > 0; o >>= 1) mq += __shfl_down(mq, o);

        if (lane == 0) {
            const float val = mq * inv_count;
            // ws layout (floats; every entity on its own 128B line):
            //   leaf lines:  ws[i*32],        i<64
            //   mid lines:   ws[2048 + j*32], j<8
            //   final line:  ws[4096]
            //   leaf cnts:   ws[8192  + i*32]
            //   mid cnts:    ws[12288 + j*32]
            //   final cnt:   ws[14336]
            const int leaf = bx & 63;            // 8 blocks per leaf
            float* leafline = ws + leaf * 32;
            cas_or_add(leafline, val);
            if (arrive((unsigned*)(ws + 8192 + leaf * 32), 8u)) {
                const float lsum = aread(leafline);
                const int mid = leaf >> 3;       // 8 leaves per mid
                float* midline = ws + 2048 + mid * 32;
                cas_or_add(midline, lsum);
                if (arrive((unsigned*)(ws + 12288 + mid * 32), 8u)) {
                    const float msum = aread(midline);
                    float* fin = ws + 4096;
                    cas_or_add(fin, msum);
                    if (arrive((unsigned*)(ws + 14336), 8u)) {
                        out[0] = aread(fin);
                    }
                }
            }
        }
    }
}

extern "C" void kernel_launch(void* const* d_in, const int* in_sizes, int n_in,
                              void* d_out, int out_size, void* d_ws, size_t ws_size,
                              hipStream_t stream) {
    const float* depth = (const float*)d_in[0];
    const float* bnd   = (const float*)d_in[1];
    float* out = (float*)d_out;
    float* ws  = (float*)d_ws;

    const int B = in_sizes[0] / N_PIX;          // 4
    const int blocks_per_dir = B * 64;          // 256
    const float inv_count = 1.0f / (float)(B * N_PIX);

    hipLaunchKernelGGL(chamfer_fused_kernel, dim3(2 * blocks_per_dir), dim3(256),
                       0, stream, depth, bnd, out, ws, blocks_per_dir, inv_count);
}

// Round 10
// 74.094 us; speedup vs baseline: 1.9842x; 1.0316x over previous
//
#include <hip/hip_runtime.h>
#include <math.h>

// ChamferLikeDistanceLoss on MI355X (gfx950)
// B=4, 1x64x64 fp32. out = mean_i min_j |g_i - b_j| + mean_j min_i |g_i - b_j|
//
// R10: attack K0 (~26us of once-executed kernel time) as COLD-I$ FETCH over
// a multi-KB unrolled prologue.
//  - Evidence: R8 rep-probe -> ring = 4.54us/pass, K0 = kernel - rep*slope
//    ~= 26us, constant. R7 (shfl->DPP), R5 (occupancy), R9 (atomic tree) all
//    neutral => K0 is not cross-lane, not occupancy, not atomics. The only
//    once-executed heavy phase left is the straight-line prologue (~700+
//    insts: unroll-16 sobel with 6 shfls + sqrt each) + possibly an unrolled
//    64-step ring. Cold I$ walk at ~300-900cy/line over several KB, paid by
//    the slowest CU cluster, is ~constant and rep-invariant -- K0's exact
//    signature. Also retro-explains R4's regression (bigger prologue).
//  - Fix: executed-once code shrunk ~5x. Sobel -> LDS via ROLLED loop
//    (#pragma unroll 1); bnd staging rolled; both dirs share one tiny
//    unrolled LDS->reg readback (4x ds_read_b128, wave-local quarters so no
//    barrier: compiler's lgkmcnt covers same-wave LDS ordering). Ring step
//    loop forced rolled. Epilogue = R7's minimal CAS-or-add.
//  - Ring engine unchanged (DPP wave_ror:1); dir-1 ref partition changes
//    (min is order-independent; absmax stays within bf16 ulps).

#define N_PIX 4096
#define POISON_U 0xAAAAAAAAu

__device__ __forceinline__ float wave_ror1(float x) {
    return __int_as_float(__builtin_amdgcn_mov_dpp(__float_as_int(x),
                                                   0x13C, 0xF, 0xF, true));
}

__device__ __forceinline__ float sobel3(float t, float c, float b, int lane) {
    const float tl = (lane > 0)  ? __shfl_up(t, 1)   : 0.f;
    const float cl = (lane > 0)  ? __shfl_up(c, 1)   : 0.f;
    const float bl = (lane > 0)  ? __shfl_up(b, 1)   : 0.f;
    const float tr = (lane < 63) ? __shfl_down(t, 1) : 0.f;
    const float cr = (lane < 63) ? __shfl_down(c, 1) : 0.f;
    const float br = (lane < 63) ? __shfl_down(b, 1) : 0.f;
    const float gx = (tl - tr) + 2.f * (cl - cr) + (bl - br);
    const float gy = (tl + 2.f * t + tr) - (bl + 2.f * b + br);
    return sqrtf(gx * gx + gy * gy + 1e-8f);
}

__global__ __launch_bounds__(256) void chamfer_fused_kernel(
    const float* __restrict__ depth, const float* __restrict__ bnd,
    float* __restrict__ out, int blocks_per_dir, float inv_count)
{
    __shared__ float refs_lds[N_PIX];   // per-wave quarters, wave-local use
    __shared__ float qmin[4][64];

    const int tid  = threadIdx.x;
    const int lane = tid & 63;
    const int w    = tid >> 6;                  // wave = ref quarter
    const int bx   = blockIdx.x;
    const int dir  = (bx >= blocks_per_dir) ? 1 : 0;
    const int rem  = dir ? (bx - blocks_per_dir) : bx;
    const int batch = rem >> 6;
    const int qblk  = rem & 63;

    const float* __restrict__ db = depth + batch * N_PIX;
    const float* __restrict__ bb = bnd   + batch * N_PIX;

    float q;

    if (dir == 0) {
        // refs quarter w = bnd floats [w*1024, w*1024+1024): rolled copy.
        const float4* __restrict__ b4 = (const float4*)bb;
        float4* l4 = (float4*)refs_lds;
        #pragma unroll 1
        for (int j = 0; j < 4; ++j)
            l4[w * 256 + j * 64 + lane] = b4[w * 256 + j * 64 + lane];
        // query: g at row qblk, x=lane.
        const float c = db[qblk * 64 + lane];
        const float t = (qblk > 0)  ? db[(qblk - 1) * 64 + lane] : 0.f;
        const float b = (qblk < 63) ? db[(qblk + 1) * 64 + lane] : 0.f;
        q = sobel3(t, c, b, lane);
    } else {
        // refs quarter w = sobel rows [w*16, w*16+16): ROLLED loop -> LDS.
        const int y0 = w * 16;
        float c = db[y0 * 64 + lane];
        float t = (y0 > 0) ? db[(y0 - 1) * 64 + lane] : 0.f;
        #pragma unroll 1
        for (int k = 0; k < 16; ++k) {
            const int y = y0 + k;
            const float b = (y < 63) ? db[(y + 1) * 64 + lane] : 0.f;
            refs_lds[y * 64 + lane] = sobel3(t, c, b, lane);
            t = c; c = b;
        }
        // query: boundary row qblk.
        q = bb[qblk * 64 + lane];
    }

    // Shared readback: this wave's quarter -> r[16] (4x ds_read_b128).
    // Wave-local (quarter written by this wave only) => no __syncthreads;
    // the compiler's lgkmcnt ordering covers same-wave LDS write->read.
    float r[16];
    const float4* __restrict__ l4r = (const float4*)refs_lds;
    #pragma unroll
    for (int k = 0; k < 4; ++k) {
        const float4 v = l4r[w * 256 + k * 64 + lane];
        r[4 * k + 0] = v.x; r[4 * k + 1] = v.y;
        r[4 * k + 2] = v.z; r[4 * k + 3] = v.w;
    }

    // Ring scan: (q,m) rotate via DPP; step loop kept rolled (small, I$-warm
    // after the first iteration).
    float m = 1e30f;
    #pragma unroll 1
    for (int step = 0; step < 64; ++step) {
        const float q_next = wave_ror1(q);
        float t0 = 1e30f, t1 = 1e30f;
        #pragma unroll
        for (int k = 0; k < 16; k += 4) {
            t0 = fminf(fminf(t0, fabsf(q - r[k + 0])), fabsf(q - r[k + 1]));
            t1 = fminf(fminf(t1, fabsf(q - r[k + 2])), fabsf(q - r[k + 3]));
        }
        m = fminf(m, fminf(t0, t1));
        m = wave_ror1(m);
        q = q_next;
    }

    qmin[w][lane] = m;
    __syncthreads();

    if (w == 0) {
        float mq = fminf(fminf(qmin[0][lane], qmin[1][lane]),
                         fminf(qmin[2][lane], qmin[3][lane]));
        #pragma unroll
        for (int o = 32; o > 0; o >>= 1) mq += __shfl_down(mq, o);
        if (lane == 0) {
            const float val = mq * inv_count;
            // CAS-or-add: first block converts the 0xAA poison, rest add.
            const unsigned old = atomicCAS((unsigned*)out, POISON_U,
                                           __float_as_uint(val));
            if (old != POISON_U) atomicAdd(out, val);
        }
    }
}

extern "C" void kernel_launch(void* const* d_in, const int* in_sizes, int n_in,
                              void* d_out, int out_size, void* d_ws, size_t ws_size,
                              hipStream_t stream) {
    const float* depth = (const float*)d_in[0];
    const float* bnd   = (const float*)d_in[1];
    float* out = (float*)d_out;

    const int B = in_sizes[0] / N_PIX;          // 4
    const int blocks_per_dir = B * 64;          // 256
    const float inv_count = 1.0f / (float)(B * N_PIX);

    hipLaunchKernelGGL(chamfer_fused_kernel, dim3(2 * blocks_per_dir), dim3(256),
                       0, stream, depth, bnd, out, blocks_per_dir, inv_count);
}